// Round 10
// baseline (1476.254 us; speedup 1.0000x reference)
//
#include <hip/hip_runtime.h>
#include <math.h>

#define NN 10000
#define NFEAT 512
#define NHID 256
#define NCLASS 40
#define NLAYERS 8
#define MAXDEG 96
#define GRID_L 625

typedef __attribute__((ext_vector_type(8))) short bf16x8;
typedef __attribute__((ext_vector_type(4))) float floatx4;
typedef __attribute__((ext_vector_type(2))) float floatx2;
typedef __attribute__((ext_vector_type(4))) unsigned short ushort4v;

__device__ __forceinline__ unsigned short f2bf(float f) {
    union { float f; unsigned int u; } v; v.f = f;
    unsigned int r = v.u + 0x7fffu + ((v.u >> 16) & 1u);  // RNE
    return (unsigned short)(r >> 16);
}
__device__ __forceinline__ float bf2f(unsigned short h) {
    union { unsigned int u; float f; } v; v.u = ((unsigned int)h) << 16;
    return v.f;
}
__device__ __forceinline__ unsigned char f2fp8(float f) {
    return (unsigned char)(__builtin_amdgcn_cvt_pk_fp8_f32(f, f, 0, false) & 0xFF);
}

// ---------------------------------------------------------------------------
// build_graph: one block per row; one pass over the 400MB dense adjacency.
// ---------------------------------------------------------------------------
__global__ __launch_bounds__(256) void build_graph(const float* __restrict__ adj,
                                                   int* __restrict__ cnt,
                                                   int* __restrict__ ell,
                                                   float* __restrict__ dinv) {
    int i = blockIdx.x;
    __shared__ int scnt;
    if (threadIdx.x == 0) scnt = 0;
    __syncthreads();
    const float4* row = (const float4*)(adj + (size_t)i * NN);
    const int nv = NN / 4;  // 2500
    int* erow = ell + (size_t)i * MAXDEG;
    for (int f = threadIdx.x; f < nv; f += 256) {
        float4 v = row[f];
        if (v.x != 0.0f) { int s = atomicAdd(&scnt, 1); if (s < MAXDEG) erow[s] = 4*f + 0; }
        if (v.y != 0.0f) { int s = atomicAdd(&scnt, 1); if (s < MAXDEG) erow[s] = 4*f + 1; }
        if (v.z != 0.0f) { int s = atomicAdd(&scnt, 1); if (s < MAXDEG) erow[s] = 4*f + 2; }
        if (v.w != 0.0f) { int s = atomicAdd(&scnt, 1); if (s < MAXDEG) erow[s] = 4*f + 3; }
    }
    __syncthreads();
    if (threadIdx.x == 0) {
        int c = scnt;
        cnt[i] = (c < MAXDEG) ? c : MAXDEG;
        dinv[i] = rsqrtf(1.0f + (float)c);
    }
}

// ---------------------------------------------------------------------------
// prep_weights:
//   w0t[n][k]  = bf16(w0[k][n])                                 (256x512)
//   Mt[l][n][k] = bf16(theta_l * cw[l][k][n] + (1-theta_l)*I)   (fold residual)
// ---------------------------------------------------------------------------
__global__ __launch_bounds__(256) void prep_weights(const float* __restrict__ w0,
                                                    const float* __restrict__ cw,
                                                    unsigned short* __restrict__ w0t,
                                                    unsigned short* __restrict__ Mt) {
    int idx = blockIdx.x * 256 + threadIdx.x;
    if (idx < 131072) {
        int n = idx >> 9, k = idx & 511;
        w0t[idx] = f2bf(w0[(size_t)k * 256 + n]);
    } else {
        int j = idx - 131072;
        int l = j >> 16;
        int r = j & 65535;
        int n = r >> 8, k = r & 255;
        float theta = logf(0.5f / (float)(l + 1) + 1.0f);
        float v = theta * cw[(size_t)l * 65536 + (size_t)k * 256 + n];
        if (k == n) v += 1.0f - theta;
        Mt[j] = f2bf(v);
    }
}

// ---------------------------------------------------------------------------
// gemm0: h0 = relu(x @ w0 + b0); reads fp32 x directly (in-reg bf16 cvt),
// writes bf16 h0 (residual path) + fp8 h0 (layer-0 gathers).
// 625 blocks x 8 waves; wave = 2 col-tiles of 16.
// ---------------------------------------------------------------------------
__global__ __launch_bounds__(512, 4) void gemm0_mfma(const float* __restrict__ x,
                                                     const unsigned short* __restrict__ w0t,
                                                     const float* __restrict__ b0,
                                                     unsigned short* __restrict__ h0b,
                                                     unsigned char* __restrict__ h08) {
    int t = threadIdx.x, wv = t >> 6, lane = t & 63;
    int lrow = lane & 15, quad = lane >> 4;
    int r0 = blockIdx.x * 16;

    bf16x8 a[16];
    const float4* xr = (const float4*)(x + (size_t)(r0 + lrow) * NFEAT) + quad * 2;
    #pragma unroll
    for (int f = 0; f < 16; ++f) {
        float4 lo = xr[f * 8];
        float4 hi = xr[f * 8 + 1];
        bf16x8 av;
        av[0] = (short)f2bf(lo.x); av[1] = (short)f2bf(lo.y);
        av[2] = (short)f2bf(lo.z); av[3] = (short)f2bf(lo.w);
        av[4] = (short)f2bf(hi.x); av[5] = (short)f2bf(hi.y);
        av[6] = (short)f2bf(hi.z); av[7] = (short)f2bf(hi.w);
        a[f] = av;
    }

    #pragma unroll 1
    for (int n = 0; n < 2; ++n) {
        int nt = wv * 2 + n;
        floatx4 acc = {0.f, 0.f, 0.f, 0.f};
        const unsigned short* wrow = w0t + (size_t)(nt * 16 + lrow) * NFEAT + quad * 8;
        #pragma unroll
        for (int f = 0; f < 16; ++f) {
            bf16x8 b = *(const bf16x8*)(wrow + f * 32);
            acc = __builtin_amdgcn_mfma_f32_16x16x32_bf16(a[f], b, acc, 0, 0, 0);
        }
        int col = nt * 16 + lrow;
        float bias = b0[col];
        #pragma unroll
        for (int r = 0; r < 4; ++r) {
            int row = r0 + quad * 4 + r;
            float o = fmaxf(acc[r] + bias, 0.f);
            h0b[(size_t)row * NHID + col] = f2bf(o);
            h08[(size_t)row * NHID + col] = f2fp8(o);
        }
    }
}

// ---------------------------------------------------------------------------
// gcn_layers: ALL 8 layers, persistent kernel, REGULAR launch.
// Co-residency by construction: launch_bounds(512,6) => 3 blocks/CU (VGPR
// capped ~85, proven sufficient by R8's identical-phase kernel); LDS 37.8KB
// => 4/CU; waves 24<=32. Capacity 768 >= 625 blocks -> all resident.
// Grid barrier: syncthreads -> t0 {release fence, atomic add, bounded relaxed
// spin, acquire fence} -> syncthreads. Fences are agent-scope (wb/inv L2)
// for cross-XCD visibility of the fp8 h ping-pong buffers.
// ---------------------------------------------------------------------------
__global__ __launch_bounds__(512, 6) void gcn_layers(
        const unsigned int* __restrict__ h08,
        unsigned int* __restrict__ hP8,
        unsigned int* __restrict__ hQ8,
        const unsigned short* __restrict__ h0b,
        const float* __restrict__ dinv,
        const int* __restrict__ cnt,
        const int* __restrict__ ell,
        const unsigned short* __restrict__ Mt,
        const float* __restrict__ w1,
        const float* __restrict__ b1,
        float* __restrict__ out,
        int* __restrict__ barrier) {
    __shared__ int            sj[16][MAXDEG];
    __shared__ float          scl[16][MAXDEG];
    __shared__ unsigned short supb[16][264];
    __shared__ float          hs[16 * 264];
    __shared__ int            sdeg[16];
    __shared__ float          sdinv[16];

    int t = threadIdx.x;
    int wv = t >> 6;
    int lane = t & 63;
    int r0 = blockIdx.x * 16;

    // ---- prologue: stage edge lists + scales once for all 8 layers ----
    for (int idx = t; idx < 16 * MAXDEG; idx += 512) {
        int lr = idx / MAXDEG, e = idx % MAXDEG;
        int i = r0 + lr;
        int d = cnt[i];
        int j = 0; float s = 0.0f;
        if (e < d) { j = ell[(size_t)i * MAXDEG + e]; s = dinv[j]; }
        sj[lr][e] = j;
        scl[lr][e] = s;
    }
    if (t < 16) {
        int i = r0 + t;
        sdeg[t] = (cnt[i] + 7) & ~7;
        sdinv[t] = dinv[i];
    }
    __syncthreads();

    const unsigned int* cur = h08;
    int lrow = lane & 15, quad = lane >> 4;

    #pragma unroll 1
    for (int l = 0; l < NLAYERS; ++l) {
        // ---- phase 1: fp8 gather + mix -> supb ----
        #pragma unroll 1
        for (int rr = 0; rr < 2; ++rr) {
            int lr = wv * 2 + rr;
            int i  = r0 + lr;
            int deg8 = sdeg[lr];
            float di = sdinv[lr];
            unsigned int su = cur[(size_t)i * 64 + lane];
            floatx2 slo = __builtin_amdgcn_cvt_pk_f32_fp8(su, false);
            floatx2 shi = __builtin_amdgcn_cvt_pk_f32_fp8(su, true);
            float4 acc;
            acc.x = di * slo.x;
            acc.y = di * slo.y;
            acc.z = di * shi.x;
            acc.w = di * shi.y;
            #pragma unroll 1
            for (int e0 = 0; e0 < deg8; e0 += 8) {
                #pragma unroll
                for (int u = 0; u < 8; ++u) {
                    int   j = sj[lr][e0 + u];
                    float s = scl[lr][e0 + u];
                    unsigned int xu = cur[(size_t)j * 64 + lane];
                    floatx2 lo = __builtin_amdgcn_cvt_pk_f32_fp8(xu, false);
                    floatx2 hi = __builtin_amdgcn_cvt_pk_f32_fp8(xu, true);
                    acc.x = fmaf(s, lo.x, acc.x);
                    acc.y = fmaf(s, lo.y, acc.y);
                    acc.z = fmaf(s, hi.x, acc.z);
                    acc.w = fmaf(s, hi.y, acc.w);
                }
            }
            ushort4v h0v = ((const ushort4v*)h0b)[(size_t)i * 64 + lane];
            ushort4v ob;
            ob.x = f2bf(0.9f * (di * acc.x) + 0.1f * bf2f(h0v.x));
            ob.y = f2bf(0.9f * (di * acc.y) + 0.1f * bf2f(h0v.y));
            ob.z = f2bf(0.9f * (di * acc.z) + 0.1f * bf2f(h0v.z));
            ob.w = f2bf(0.9f * (di * acc.w) + 0.1f * bf2f(h0v.w));
            *(ushort4v*)&supb[lr][4 * lane] = ob;
        }
        __syncthreads();

        // ---- phase 2: MFMA GEMM, relu epilogue (residual folded in M) ----
        bf16x8 a[8];
        #pragma unroll
        for (int f = 0; f < 8; ++f)
            a[f] = *(const bf16x8*)&supb[lrow][quad * 8 + f * 32];

        unsigned int* nxt = (l & 1) ? hQ8 : hP8;
        unsigned char* nxtb = (unsigned char*)nxt;
        const unsigned short* Ml = Mt + (size_t)l * NHID * NHID;
        #pragma unroll 1
        for (int n = 0; n < 2; ++n) {
            int nt = wv * 2 + n;
            floatx4 acc = {0.f, 0.f, 0.f, 0.f};
            const unsigned short* wrow = Ml + (size_t)(nt * 16 + lrow) * NHID + quad * 8;
            #pragma unroll
            for (int f = 0; f < 8; ++f) {
                bf16x8 b = *(const bf16x8*)(wrow + f * 32);
                acc = __builtin_amdgcn_mfma_f32_16x16x32_bf16(a[f], b, acc, 0, 0, 0);
            }
            int col = nt * 16 + lrow;
            #pragma unroll
            for (int r = 0; r < 4; ++r) {
                int lr2 = quad * 4 + r;
                float o = fmaxf(acc[r], 0.f);
                if (l == NLAYERS - 1) {
                    hs[lr2 * 264 + col] = o;
                } else {
                    nxtb[(size_t)(r0 + lr2) * NHID + col] = f2fp8(o);
                }
            }
        }

        if (l < NLAYERS - 1) {
            // ---- grid barrier (all 625 blocks co-resident) ----
            __syncthreads();
            if (t == 0) {
                __threadfence();   // agent release: wb local L2
                __hip_atomic_fetch_add(&barrier[l], 1, __ATOMIC_RELEASE,
                                       __HIP_MEMORY_SCOPE_AGENT);
                int it = 0;
                while (__hip_atomic_load(&barrier[l], __ATOMIC_RELAXED,
                                         __HIP_MEMORY_SCOPE_AGENT) < GRID_L) {
                    __builtin_amdgcn_s_sleep(4);
                    if (++it > (1 << 24)) break;   // visible-failure escape hatch
                }
                __threadfence();   // agent acquire: inv L1/L2 before next gathers
            }
            __syncthreads();
            cur = nxt;
        }
    }

    // ---- final: logits + log_softmax (block-local rows) ----
    __syncthreads();
    #pragma unroll 1
    for (int rr = 0; rr < 2; ++rr) {
        int lr = wv * 2 + rr;
        const float* hr = hs + lr * 264;
        float logit = -1e30f;
        if (lane < NCLASS) {
            float acc = b1[lane];
            #pragma unroll 8
            for (int k = 0; k < NHID; ++k)
                acc = fmaf(hr[k], w1[k * NCLASS + lane], acc);
            logit = acc;
        }
        float m = logit;
        #pragma unroll
        for (int off = 32; off > 0; off >>= 1)
            m = fmaxf(m, __shfl_xor(m, off, 64));
        float e = (lane < NCLASS) ? expf(logit - m) : 0.0f;
        float ssum = e;
        #pragma unroll
        for (int off = 32; off > 0; off >>= 1)
            ssum += __shfl_xor(ssum, off, 64);
        float lse = m + logf(ssum);
        if (lane < NCLASS)
            out[(size_t)(r0 + lr) * NCLASS + lane] = logit - lse;
    }
}

// ---------------------------------------------------------------------------
extern "C" void kernel_launch(void* const* d_in, const int* in_sizes, int n_in,
                              void* d_out, int out_size, void* d_ws, size_t ws_size,
                              hipStream_t stream) {
    const float* x      = (const float*)d_in[0];
    const float* adj    = (const float*)d_in[1];
    const float* w0     = (const float*)d_in[2];
    const float* b0     = (const float*)d_in[3];
    const float* conv_w = (const float*)d_in[4];
    const float* w1     = (const float*)d_in[5];
    const float* b1     = (const float*)d_in[6];
    float* out = (float*)d_out;

    char* ws = (char*)d_ws;
    size_t off = 0;
    auto alloc = [&](size_t bytes) -> void* {
        void* p = ws + off;
        off = (off + bytes + 255) & ~(size_t)255;
        return p;
    };
    float*          dinv  = (float*)alloc((size_t)NN * 4);
    int*            cnt   = (int*)  alloc((size_t)NN * 4);
    int*            ell   = (int*)  alloc((size_t)NN * MAXDEG * 4);
    unsigned short* w0t   = (unsigned short*)alloc((size_t)NFEAT * NHID * 2);
    unsigned short* Mt    = (unsigned short*)alloc((size_t)NLAYERS * NHID * NHID * 2);
    unsigned short* h0b   = (unsigned short*)alloc((size_t)NN * NHID * 2);
    unsigned int*   h08   = (unsigned int*)alloc((size_t)NN * NHID);
    unsigned int*   hP8   = (unsigned int*)alloc((size_t)NN * NHID);
    unsigned int*   hQ8   = (unsigned int*)alloc((size_t)NN * NHID);
    int*            barrier = (int*)alloc(64 * 4);

    hipMemsetAsync(barrier, 0, 64 * 4, stream);  // counters must start at 0

    build_graph<<<NN, 256, 0, stream>>>(adj, cnt, ell, dinv);
    prep_weights<<<(131072 + NLAYERS * NHID * NHID) / 256, 256, 0, stream>>>(w0, conv_w, w0t, Mt);
    gemm0_mfma<<<NN / 16, 512, 0, stream>>>(x, w0t, b0, h0b, (unsigned char*)h08);

    gcn_layers<<<GRID_L, 512, 0, stream>>>(h08, hP8, hQ8, h0b, dinv, cnt, ell,
                                           Mt, w1, b1, out, barrier);
}

// Round 11
// 1160.730 us; speedup vs baseline: 1.2718x; 1.2718x over previous
//
#include <hip/hip_runtime.h>
#include <math.h>

#define NN 10000
#define NFEAT 512
#define NHID 256
#define NCLASS 40
#define NLAYERS 8
#define MAXDEG 96
#define GRID_L 625

typedef __attribute__((ext_vector_type(8))) short bf16x8;
typedef __attribute__((ext_vector_type(4))) float floatx4;
typedef __attribute__((ext_vector_type(2))) float floatx2;
typedef __attribute__((ext_vector_type(4))) unsigned short ushort4v;

__device__ __forceinline__ unsigned short f2bf(float f) {
    union { float f; unsigned int u; } v; v.f = f;
    unsigned int r = v.u + 0x7fffu + ((v.u >> 16) & 1u);  // RNE
    return (unsigned short)(r >> 16);
}
__device__ __forceinline__ float bf2f(unsigned short h) {
    union { unsigned int u; float f; } v; v.u = ((unsigned int)h) << 16;
    return v.f;
}
__device__ __forceinline__ unsigned char f2fp8(float f) {
    return (unsigned char)(__builtin_amdgcn_cvt_pk_fp8_f32(f, f, 0, false) & 0xFF);
}
// LLC-coherent (L2-bypassing) access for cross-XCD shared h buffers
__device__ __forceinline__ unsigned int llc_load(const unsigned int* p) {
    return __hip_atomic_load(p, __ATOMIC_RELAXED, __HIP_MEMORY_SCOPE_AGENT);
}
__device__ __forceinline__ void llc_store(unsigned int* p, unsigned int v) {
    __hip_atomic_store(p, v, __ATOMIC_RELAXED, __HIP_MEMORY_SCOPE_AGENT);
}

// ---------------------------------------------------------------------------
// build_graph: one block per row; one pass over the 400MB dense adjacency.
// ---------------------------------------------------------------------------
__global__ __launch_bounds__(256) void build_graph(const float* __restrict__ adj,
                                                   int* __restrict__ cnt,
                                                   int* __restrict__ ell,
                                                   float* __restrict__ dinv) {
    int i = blockIdx.x;
    __shared__ int scnt;
    if (threadIdx.x == 0) scnt = 0;
    __syncthreads();
    const float4* row = (const float4*)(adj + (size_t)i * NN);
    const int nv = NN / 4;  // 2500
    int* erow = ell + (size_t)i * MAXDEG;
    for (int f = threadIdx.x; f < nv; f += 256) {
        float4 v = row[f];
        if (v.x != 0.0f) { int s = atomicAdd(&scnt, 1); if (s < MAXDEG) erow[s] = 4*f + 0; }
        if (v.y != 0.0f) { int s = atomicAdd(&scnt, 1); if (s < MAXDEG) erow[s] = 4*f + 1; }
        if (v.z != 0.0f) { int s = atomicAdd(&scnt, 1); if (s < MAXDEG) erow[s] = 4*f + 2; }
        if (v.w != 0.0f) { int s = atomicAdd(&scnt, 1); if (s < MAXDEG) erow[s] = 4*f + 3; }
    }
    __syncthreads();
    if (threadIdx.x == 0) {
        int c = scnt;
        cnt[i] = (c < MAXDEG) ? c : MAXDEG;
        dinv[i] = rsqrtf(1.0f + (float)c);
    }
}

// ---------------------------------------------------------------------------
// prep_weights:
//   w0t[n][k]  = bf16(w0[k][n])                                 (256x512)
//   Mt[l][n][k] = bf16(theta_l * cw[l][k][n] + (1-theta_l)*I)   (fold residual)
// ---------------------------------------------------------------------------
__global__ __launch_bounds__(256) void prep_weights(const float* __restrict__ w0,
                                                    const float* __restrict__ cw,
                                                    unsigned short* __restrict__ w0t,
                                                    unsigned short* __restrict__ Mt) {
    int idx = blockIdx.x * 256 + threadIdx.x;
    if (idx < 131072) {
        int n = idx >> 9, k = idx & 511;
        w0t[idx] = f2bf(w0[(size_t)k * 256 + n]);
    } else {
        int j = idx - 131072;
        int l = j >> 16;
        int r = j & 65535;
        int n = r >> 8, k = r & 255;
        float theta = logf(0.5f / (float)(l + 1) + 1.0f);
        float v = theta * cw[(size_t)l * 65536 + (size_t)k * 256 + n];
        if (k == n) v += 1.0f - theta;
        Mt[j] = f2bf(v);
    }
}

// ---------------------------------------------------------------------------
// gemm0: h0 = relu(x @ w0 + b0); reads fp32 x directly (in-reg bf16 cvt),
// writes bf16 h0 (residual path) + fp8 h0 (layer-0 gathers).
// ---------------------------------------------------------------------------
__global__ __launch_bounds__(512, 4) void gemm0_mfma(const float* __restrict__ x,
                                                     const unsigned short* __restrict__ w0t,
                                                     const float* __restrict__ b0,
                                                     unsigned short* __restrict__ h0b,
                                                     unsigned char* __restrict__ h08) {
    int t = threadIdx.x, wv = t >> 6, lane = t & 63;
    int lrow = lane & 15, quad = lane >> 4;
    int r0 = blockIdx.x * 16;

    bf16x8 a[16];
    const float4* xr = (const float4*)(x + (size_t)(r0 + lrow) * NFEAT) + quad * 2;
    #pragma unroll
    for (int f = 0; f < 16; ++f) {
        float4 lo = xr[f * 8];
        float4 hi = xr[f * 8 + 1];
        bf16x8 av;
        av[0] = (short)f2bf(lo.x); av[1] = (short)f2bf(lo.y);
        av[2] = (short)f2bf(lo.z); av[3] = (short)f2bf(lo.w);
        av[4] = (short)f2bf(hi.x); av[5] = (short)f2bf(hi.y);
        av[6] = (short)f2bf(hi.z); av[7] = (short)f2bf(hi.w);
        a[f] = av;
    }

    #pragma unroll 1
    for (int n = 0; n < 2; ++n) {
        int nt = wv * 2 + n;
        floatx4 acc = {0.f, 0.f, 0.f, 0.f};
        const unsigned short* wrow = w0t + (size_t)(nt * 16 + lrow) * NFEAT + quad * 8;
        #pragma unroll
        for (int f = 0; f < 16; ++f) {
            bf16x8 b = *(const bf16x8*)(wrow + f * 32);
            acc = __builtin_amdgcn_mfma_f32_16x16x32_bf16(a[f], b, acc, 0, 0, 0);
        }
        int col = nt * 16 + lrow;
        float bias = b0[col];
        #pragma unroll
        for (int r = 0; r < 4; ++r) {
            int row = r0 + quad * 4 + r;
            float o = fmaxf(acc[r] + bias, 0.f);
            h0b[(size_t)row * NHID + col] = f2bf(o);
            h08[(size_t)row * NHID + col] = f2fp8(o);
        }
    }
}

// ---------------------------------------------------------------------------
// gcn_layers: ALL 8 layers, persistent, regular launch.
// Co-residency proven on HW (R10: correct barrier completion at this exact
// occupancy: launch_bounds(512,6), 37.9KB LDS, 625 blocks <= 768 capacity).
// Cross-XCD coherence WITHOUT cache maintenance: the h ping-pong buffers are
// accessed exclusively via agent-scope relaxed atomics (L2-bypass, LLC
// coherent). __syncthreads drains vmcnt before the t0 counter add, so the
// barrier needs no __threadfence (R10's 897us fence storm eliminated).
// ---------------------------------------------------------------------------
__global__ __launch_bounds__(512, 6) void gcn_layers(
        const unsigned int* __restrict__ h08,
        unsigned int* __restrict__ hP8,
        unsigned int* __restrict__ hQ8,
        const unsigned short* __restrict__ h0b,
        const float* __restrict__ dinv,
        const int* __restrict__ cnt,
        const int* __restrict__ ell,
        const unsigned short* __restrict__ Mt,
        const float* __restrict__ w1,
        const float* __restrict__ b1,
        float* __restrict__ out,
        int* __restrict__ barrier) {
    __shared__ int            sj[16][MAXDEG];
    __shared__ float          scl[16][MAXDEG];
    __shared__ unsigned short supb[16][264];
    __shared__ float          hs[16 * 268];     // stride 268: quad-dim 2-way only
    __shared__ int            sdeg[16];
    __shared__ float          sdinv[16];

    int t = threadIdx.x;
    int wv = t >> 6;
    int lane = t & 63;
    int r0 = blockIdx.x * 16;

    // ---- prologue: stage edge lists + scales once for all 8 layers ----
    for (int idx = t; idx < 16 * MAXDEG; idx += 512) {
        int lr = idx / MAXDEG, e = idx % MAXDEG;
        int i = r0 + lr;
        int d = cnt[i];
        int j = 0; float s = 0.0f;
        if (e < d) { j = ell[(size_t)i * MAXDEG + e]; s = dinv[j]; }
        sj[lr][e] = j;
        scl[lr][e] = s;
    }
    if (t < 16) {
        int i = r0 + t;
        sdeg[t] = (cnt[i] + 7) & ~7;
        sdinv[t] = dinv[i];
    }
    __syncthreads();

    const unsigned int* cur = h08;
    int lrow = lane & 15, quad = lane >> 4;

    #pragma unroll 1
    for (int l = 0; l < NLAYERS; ++l) {
        // ---- phase 1: fp8 gather (LLC-coherent loads) + mix -> supb ----
        #pragma unroll 1
        for (int rr = 0; rr < 2; ++rr) {
            int lr = wv * 2 + rr;
            int i  = r0 + lr;
            int deg8 = sdeg[lr];
            float di = sdinv[lr];
            unsigned int su = llc_load(&cur[(size_t)i * 64 + lane]);
            floatx2 slo = __builtin_amdgcn_cvt_pk_f32_fp8(su, false);
            floatx2 shi = __builtin_amdgcn_cvt_pk_f32_fp8(su, true);
            float4 acc;
            acc.x = di * slo.x;
            acc.y = di * slo.y;
            acc.z = di * shi.x;
            acc.w = di * shi.y;
            #pragma unroll 1
            for (int e0 = 0; e0 < deg8; e0 += 8) {
                #pragma unroll
                for (int u = 0; u < 8; ++u) {
                    int   j = sj[lr][e0 + u];
                    float s = scl[lr][e0 + u];
                    unsigned int xu = llc_load(&cur[(size_t)j * 64 + lane]);
                    floatx2 lo = __builtin_amdgcn_cvt_pk_f32_fp8(xu, false);
                    floatx2 hi = __builtin_amdgcn_cvt_pk_f32_fp8(xu, true);
                    acc.x = fmaf(s, lo.x, acc.x);
                    acc.y = fmaf(s, lo.y, acc.y);
                    acc.z = fmaf(s, hi.x, acc.z);
                    acc.w = fmaf(s, hi.y, acc.w);
                }
            }
            ushort4v h0v = ((const ushort4v*)h0b)[(size_t)i * 64 + lane];
            ushort4v ob;
            ob.x = f2bf(0.9f * (di * acc.x) + 0.1f * bf2f(h0v.x));
            ob.y = f2bf(0.9f * (di * acc.y) + 0.1f * bf2f(h0v.y));
            ob.z = f2bf(0.9f * (di * acc.z) + 0.1f * bf2f(h0v.z));
            ob.w = f2bf(0.9f * (di * acc.w) + 0.1f * bf2f(h0v.w));
            *(ushort4v*)&supb[lr][4 * lane] = ob;
        }
        __syncthreads();

        // ---- phase 2: MFMA GEMM -> hs (LDS fp32), relu epilogue ----
        bf16x8 a[8];
        #pragma unroll
        for (int f = 0; f < 8; ++f)
            a[f] = *(const bf16x8*)&supb[lrow][quad * 8 + f * 32];

        const unsigned short* Ml = Mt + (size_t)l * NHID * NHID;
        #pragma unroll 1
        for (int n = 0; n < 2; ++n) {
            int nt = wv * 2 + n;
            floatx4 acc = {0.f, 0.f, 0.f, 0.f};
            const unsigned short* wrow = Ml + (size_t)(nt * 16 + lrow) * NHID + quad * 8;
            #pragma unroll
            for (int f = 0; f < 8; ++f) {
                bf16x8 b = *(const bf16x8*)(wrow + f * 32);
                acc = __builtin_amdgcn_mfma_f32_16x16x32_bf16(a[f], b, acc, 0, 0, 0);
            }
            int col = nt * 16 + lrow;
            #pragma unroll
            for (int r = 0; r < 4; ++r) {
                int lr2 = quad * 4 + r;
                hs[lr2 * 268 + col] = fmaxf(acc[r], 0.f);
            }
        }
        __syncthreads();

        if (l < NLAYERS - 1) {
            // ---- pack hs -> fp8 uints, LLC-coherent coalesced stores ----
            unsigned int* nxt = (l & 1) ? hQ8 : hP8;
            #pragma unroll
            for (int q = 0; q < 2; ++q) {
                int u = t * 2 + q;            // 0..1023
                int row = u >> 6;
                int cq = u & 63;
                const float* p = hs + row * 268 + cq * 4;
                unsigned int pk = __builtin_amdgcn_cvt_pk_fp8_f32(p[0], p[1], 0, false);
                pk = __builtin_amdgcn_cvt_pk_fp8_f32(p[2], p[3], pk, true);
                llc_store(&nxt[(size_t)(r0 + row) * 64 + cq], pk);
            }
            // ---- grid barrier: syncthreads drains vmcnt (stores at LLC);
            //      t0 relaxed add + relaxed spin; no cache maintenance ----
            __syncthreads();
            if (t == 0) {
                __hip_atomic_fetch_add(&barrier[l], 1, __ATOMIC_RELAXED,
                                       __HIP_MEMORY_SCOPE_AGENT);
                int it = 0;
                while (__hip_atomic_load(&barrier[l], __ATOMIC_RELAXED,
                                         __HIP_MEMORY_SCOPE_AGENT) < GRID_L) {
                    __builtin_amdgcn_s_sleep(4);
                    if (++it > (1 << 24)) break;   // visible-failure escape hatch
                }
            }
            __syncthreads();
            cur = nxt;
        }
    }

    // ---- final: logits + log_softmax (block-local rows, hs resident) ----
    #pragma unroll 1
    for (int rr = 0; rr < 2; ++rr) {
        int lr = wv * 2 + rr;
        const float* hr = hs + lr * 268;
        float logit = -1e30f;
        if (lane < NCLASS) {
            float acc = b1[lane];
            #pragma unroll 8
            for (int k = 0; k < NHID; ++k)
                acc = fmaf(hr[k], w1[k * NCLASS + lane], acc);
            logit = acc;
        }
        float m = logit;
        #pragma unroll
        for (int off = 32; off > 0; off >>= 1)
            m = fmaxf(m, __shfl_xor(m, off, 64));
        float e = (lane < NCLASS) ? expf(logit - m) : 0.0f;
        float ssum = e;
        #pragma unroll
        for (int off = 32; off > 0; off >>= 1)
            ssum += __shfl_xor(ssum, off, 64);
        float lse = m + logf(ssum);
        if (lane < NCLASS)
            out[(size_t)(r0 + lr) * NCLASS + lane] = logit - lse;
    }
}

// ---------------------------------------------------------------------------
extern "C" void kernel_launch(void* const* d_in, const int* in_sizes, int n_in,
                              void* d_out, int out_size, void* d_ws, size_t ws_size,
                              hipStream_t stream) {
    const float* x      = (const float*)d_in[0];
    const float* adj    = (const float*)d_in[1];
    const float* w0     = (const float*)d_in[2];
    const float* b0     = (const float*)d_in[3];
    const float* conv_w = (const float*)d_in[4];
    const float* w1     = (const float*)d_in[5];
    const float* b1     = (const float*)d_in[6];
    float* out = (float*)d_out;

    char* ws = (char*)d_ws;
    size_t off = 0;
    auto alloc = [&](size_t bytes) -> void* {
        void* p = ws + off;
        off = (off + bytes + 255) & ~(size_t)255;
        return p;
    };
    float*          dinv  = (float*)alloc((size_t)NN * 4);
    int*            cnt   = (int*)  alloc((size_t)NN * 4);
    int*            ell   = (int*)  alloc((size_t)NN * MAXDEG * 4);
    unsigned short* w0t   = (unsigned short*)alloc((size_t)NFEAT * NHID * 2);
    unsigned short* Mt    = (unsigned short*)alloc((size_t)NLAYERS * NHID * NHID * 2);
    unsigned short* h0b   = (unsigned short*)alloc((size_t)NN * NHID * 2);
    unsigned int*   h08   = (unsigned int*)alloc((size_t)NN * NHID);
    unsigned int*   hP8   = (unsigned int*)alloc((size_t)NN * NHID);
    unsigned int*   hQ8   = (unsigned int*)alloc((size_t)NN * NHID);
    int*            barrier = (int*)alloc(64 * 4);

    hipMemsetAsync(barrier, 0, 64 * 4, stream);  // counters must start at 0

    build_graph<<<NN, 256, 0, stream>>>(adj, cnt, ell, dinv);
    prep_weights<<<(131072 + NLAYERS * NHID * NHID) / 256, 256, 0, stream>>>(w0, conv_w, w0t, Mt);
    gemm0_mfma<<<NN / 16, 512, 0, stream>>>(x, w0t, b0, h0b, (unsigned char*)h08);

    gcn_layers<<<GRID_L, 512, 0, stream>>>(h08, hP8, hQ8, h0b, dinv, cnt, ell,
                                           Mt, w1, b1, out, barrier);
}

// Round 12
// 787.685 us; speedup vs baseline: 1.8742x; 1.4736x over previous
//
#include <hip/hip_runtime.h>
#include <math.h>

#define NN 10000
#define NFEAT 512
#define NHID 256
#define NCLASS 40
#define NLAYERS 8
#define MAXDEG 96

typedef __attribute__((ext_vector_type(8))) short bf16x8;
typedef __attribute__((ext_vector_type(4))) float floatx4;
typedef __attribute__((ext_vector_type(2))) float floatx2;
typedef __attribute__((ext_vector_type(4))) unsigned short ushort4v;

__device__ __forceinline__ unsigned short f2bf(float f) {
    union { float f; unsigned int u; } v; v.f = f;
    unsigned int r = v.u + 0x7fffu + ((v.u >> 16) & 1u);  // RNE
    return (unsigned short)(r >> 16);
}
__device__ __forceinline__ float bf2f(unsigned short h) {
    union { unsigned int u; float f; } v; v.u = ((unsigned int)h) << 16;
    return v.f;
}
__device__ __forceinline__ unsigned char f2fp8(float f) {
    return (unsigned char)(__builtin_amdgcn_cvt_pk_fp8_f32(f, f, 0, false) & 0xFF);
}

// ---------------------------------------------------------------------------
// build_graph: one block per row; one pass over the 400MB dense adjacency.
// ---------------------------------------------------------------------------
__global__ __launch_bounds__(256) void build_graph(const float* __restrict__ adj,
                                                   int* __restrict__ cnt,
                                                   int* __restrict__ ell,
                                                   float* __restrict__ dinv) {
    int i = blockIdx.x;
    __shared__ int scnt;
    if (threadIdx.x == 0) scnt = 0;
    __syncthreads();
    const float4* row = (const float4*)(adj + (size_t)i * NN);
    const int nv = NN / 4;  // 2500
    int* erow = ell + (size_t)i * MAXDEG;
    for (int f = threadIdx.x; f < nv; f += 256) {
        float4 v = row[f];
        if (v.x != 0.0f) { int s = atomicAdd(&scnt, 1); if (s < MAXDEG) erow[s] = 4*f + 0; }
        if (v.y != 0.0f) { int s = atomicAdd(&scnt, 1); if (s < MAXDEG) erow[s] = 4*f + 1; }
        if (v.z != 0.0f) { int s = atomicAdd(&scnt, 1); if (s < MAXDEG) erow[s] = 4*f + 2; }
        if (v.w != 0.0f) { int s = atomicAdd(&scnt, 1); if (s < MAXDEG) erow[s] = 4*f + 3; }
    }
    __syncthreads();
    if (threadIdx.x == 0) {
        int c = scnt;
        cnt[i] = (c < MAXDEG) ? c : MAXDEG;
        dinv[i] = rsqrtf(1.0f + (float)c);
    }
}

// ---------------------------------------------------------------------------
// prep_ell: scl_g[i][e] = dinv[ell[i][e]] for e<deg, else 0; ell 0-padded so
// the gather loop can run in fixed groups of 8 with 0-scaled extras.
// ---------------------------------------------------------------------------
__global__ __launch_bounds__(256) void prep_ell(int* __restrict__ ell,
                                                const int* __restrict__ cnt,
                                                const float* __restrict__ dinv,
                                                float* __restrict__ scl_g) {
    int idx = blockIdx.x * 256 + threadIdx.x;   // 960000 total
    if (idx >= NN * MAXDEG) return;
    int i = idx / MAXDEG, e = idx % MAXDEG;
    if (e < cnt[i]) {
        scl_g[idx] = dinv[ell[idx]];
    } else {
        scl_g[idx] = 0.0f;
        ell[idx] = 0;            // safe dummy row, scale 0
    }
}

// ---------------------------------------------------------------------------
// prep_weights:
//   w0t[n][k]  = bf16(w0[k][n])                                 (256x512)
//   Mt[l][n][k] = bf16(theta_l * cw[l][k][n] + (1-theta_l)*I)   (fold residual)
// ---------------------------------------------------------------------------
__global__ __launch_bounds__(256) void prep_weights(const float* __restrict__ w0,
                                                    const float* __restrict__ cw,
                                                    unsigned short* __restrict__ w0t,
                                                    unsigned short* __restrict__ Mt) {
    int idx = blockIdx.x * 256 + threadIdx.x;
    if (idx < 131072) {
        int n = idx >> 9, k = idx & 511;
        w0t[idx] = f2bf(w0[(size_t)k * 256 + n]);
    } else {
        int j = idx - 131072;
        int l = j >> 16;
        int r = j & 65535;
        int n = r >> 8, k = r & 255;
        float theta = logf(0.5f / (float)(l + 1) + 1.0f);
        float v = theta * cw[(size_t)l * 65536 + (size_t)k * 256 + n];
        if (k == n) v += 1.0f - theta;
        Mt[j] = f2bf(v);
    }
}

// ---------------------------------------------------------------------------
// gemm0: h0 = relu(x @ w0 + b0); reads fp32 x directly (in-reg bf16 cvt),
// writes bf16 h0 (residual path) + fp8 h0 (layer-0 gathers).  [proven R10]
// ---------------------------------------------------------------------------
__global__ __launch_bounds__(512, 4) void gemm0_mfma(const float* __restrict__ x,
                                                     const unsigned short* __restrict__ w0t,
                                                     const float* __restrict__ b0,
                                                     unsigned short* __restrict__ h0b,
                                                     unsigned char* __restrict__ h08) {
    int t = threadIdx.x, wv = t >> 6, lane = t & 63;
    int lrow = lane & 15, quad = lane >> 4;
    int r0 = blockIdx.x * 16;

    bf16x8 a[16];
    const float4* xr = (const float4*)(x + (size_t)(r0 + lrow) * NFEAT) + quad * 2;
    #pragma unroll
    for (int f = 0; f < 16; ++f) {
        float4 lo = xr[f * 8];
        float4 hi = xr[f * 8 + 1];
        bf16x8 av;
        av[0] = (short)f2bf(lo.x); av[1] = (short)f2bf(lo.y);
        av[2] = (short)f2bf(lo.z); av[3] = (short)f2bf(lo.w);
        av[4] = (short)f2bf(hi.x); av[5] = (short)f2bf(hi.y);
        av[6] = (short)f2bf(hi.z); av[7] = (short)f2bf(hi.w);
        a[f] = av;
    }

    #pragma unroll 1
    for (int n = 0; n < 2; ++n) {
        int nt = wv * 2 + n;
        floatx4 acc = {0.f, 0.f, 0.f, 0.f};
        const unsigned short* wrow = w0t + (size_t)(nt * 16 + lrow) * NFEAT + quad * 8;
        #pragma unroll
        for (int f = 0; f < 16; ++f) {
            bf16x8 b = *(const bf16x8*)(wrow + f * 32);
            acc = __builtin_amdgcn_mfma_f32_16x16x32_bf16(a[f], b, acc, 0, 0, 0);
        }
        int col = nt * 16 + lrow;
        float bias = b0[col];
        #pragma unroll
        for (int r = 0; r < 4; ++r) {
            int row = r0 + quad * 4 + r;
            float o = fmaxf(acc[r] + bias, 0.f);
            h0b[(size_t)row * NHID + col] = f2bf(o);
            h08[(size_t)row * NHID + col] = f2fp8(o);
        }
    }
}

// ---------------------------------------------------------------------------
// layer_fused (split, per layer; R8 structure): block = 16 rows, 8 waves.
// Phase 1: wave handles its 2 rows INTERLEAVED in one gather loop — 16 loads
//   in flight instead of 8, wall = max(row chains) not sum. Per-row fma
//   order unchanged -> bit-identical numerics vs R8.
// Phase 2: wave = 2 col-tiles; out = relu(sup @ M), M pre-folded; fp8 out.
// LAST: out tile -> LDS fp32, in-block logits + log_softmax -> out.
// ---------------------------------------------------------------------------
template<bool LAST>
__global__ __launch_bounds__(512, 6) void layer_fused(const unsigned int* __restrict__ h8,
                                                      const unsigned short* __restrict__ h0b,
                                                      const float* __restrict__ dinv,
                                                      const int* __restrict__ cnt,
                                                      const int* __restrict__ ell,
                                                      const float* __restrict__ scl_g,
                                                      const unsigned short* __restrict__ Mt,
                                                      const float* __restrict__ w1,
                                                      const float* __restrict__ b1,
                                                      unsigned char* __restrict__ h8_out,
                                                      float* __restrict__ out) {
    __shared__ unsigned short supb[16][264];
    __shared__ float hs[LAST ? 16 * 264 : 4];

    int t = threadIdx.x;
    int wv = __builtin_amdgcn_readfirstlane(t >> 6);   // wave-uniform in SGPR
    int lane = t & 63;
    int r0 = blockIdx.x * 16;

    // ---- phase 1: dual-row interleaved fp8 gather + mix -> supb ----
    {
        int lrA = wv * 2, lrB = wv * 2 + 1;
        int iA = r0 + lrA, iB = r0 + lrB;
        int degA = (cnt[iA] + 7) & ~7;
        int degB = (cnt[iB] + 7) & ~7;
        int maxd = degA > degB ? degA : degB;          // <= MAXDEG; pads are x0.0
        float diA = dinv[iA], diB = dinv[iB];
        const int*   ellA = ell   + (size_t)iA * MAXDEG;
        const float* sclA = scl_g + (size_t)iA * MAXDEG;
        const int*   ellB = ell   + (size_t)iB * MAXDEG;
        const float* sclB = scl_g + (size_t)iB * MAXDEG;

        unsigned int suA = h8[(size_t)iA * 64 + lane];
        unsigned int suB = h8[(size_t)iB * 64 + lane];
        floatx2 alo = __builtin_amdgcn_cvt_pk_f32_fp8(suA, false);
        floatx2 ahi = __builtin_amdgcn_cvt_pk_f32_fp8(suA, true);
        floatx2 blo = __builtin_amdgcn_cvt_pk_f32_fp8(suB, false);
        floatx2 bhi = __builtin_amdgcn_cvt_pk_f32_fp8(suB, true);
        float4 accA, accB;
        accA.x = diA * alo.x; accA.y = diA * alo.y;
        accA.z = diA * ahi.x; accA.w = diA * ahi.y;
        accB.x = diB * blo.x; accB.y = diB * blo.y;
        accB.z = diB * bhi.x; accB.w = diB * bhi.y;

        #pragma unroll 1
        for (int e0 = 0; e0 < maxd; e0 += 8) {
            #pragma unroll
            for (int u = 0; u < 8; ++u) {
                int   jA = ellA[e0 + u];               // uniform -> s_load
                int   jB = ellB[e0 + u];
                float sA = sclA[e0 + u];
                float sB = sclB[e0 + u];
                unsigned int xA = h8[(size_t)jA * 64 + lane];
                unsigned int xB = h8[(size_t)jB * 64 + lane];
                floatx2 lo, hi;
                lo = __builtin_amdgcn_cvt_pk_f32_fp8(xA, false);
                hi = __builtin_amdgcn_cvt_pk_f32_fp8(xA, true);
                accA.x = fmaf(sA, lo.x, accA.x);
                accA.y = fmaf(sA, lo.y, accA.y);
                accA.z = fmaf(sA, hi.x, accA.z);
                accA.w = fmaf(sA, hi.y, accA.w);
                lo = __builtin_amdgcn_cvt_pk_f32_fp8(xB, false);
                hi = __builtin_amdgcn_cvt_pk_f32_fp8(xB, true);
                accB.x = fmaf(sB, lo.x, accB.x);
                accB.y = fmaf(sB, lo.y, accB.y);
                accB.z = fmaf(sB, hi.x, accB.z);
                accB.w = fmaf(sB, hi.y, accB.w);
            }
        }
        ushort4v h0A = ((const ushort4v*)h0b)[(size_t)iA * 64 + lane];
        ushort4v h0B = ((const ushort4v*)h0b)[(size_t)iB * 64 + lane];
        ushort4v oA, oB;
        oA.x = f2bf(0.9f * (diA * accA.x) + 0.1f * bf2f(h0A.x));
        oA.y = f2bf(0.9f * (diA * accA.y) + 0.1f * bf2f(h0A.y));
        oA.z = f2bf(0.9f * (diA * accA.z) + 0.1f * bf2f(h0A.z));
        oA.w = f2bf(0.9f * (diA * accA.w) + 0.1f * bf2f(h0A.w));
        oB.x = f2bf(0.9f * (diB * accB.x) + 0.1f * bf2f(h0B.x));
        oB.y = f2bf(0.9f * (diB * accB.y) + 0.1f * bf2f(h0B.y));
        oB.z = f2bf(0.9f * (diB * accB.z) + 0.1f * bf2f(h0B.z));
        oB.w = f2bf(0.9f * (diB * accB.w) + 0.1f * bf2f(h0B.w));
        *(ushort4v*)&supb[lrA][4 * lane] = oA;
        *(ushort4v*)&supb[lrB][4 * lane] = oB;
    }
    __syncthreads();

    // ---- phase 2: MFMA GEMM, relu epilogue (residual folded in M) ----
    int lrow = lane & 15, quad = lane >> 4;
    bf16x8 a[8];
    #pragma unroll
    for (int f = 0; f < 8; ++f)
        a[f] = *(const bf16x8*)&supb[lrow][quad * 8 + f * 32];

    #pragma unroll 1
    for (int n = 0; n < 2; ++n) {
        int nt = wv * 2 + n;
        floatx4 acc = {0.f, 0.f, 0.f, 0.f};
        const unsigned short* wrow = Mt + (size_t)(nt * 16 + lrow) * NHID + quad * 8;
        #pragma unroll
        for (int f = 0; f < 8; ++f) {
            bf16x8 b = *(const bf16x8*)(wrow + f * 32);
            acc = __builtin_amdgcn_mfma_f32_16x16x32_bf16(a[f], b, acc, 0, 0, 0);
        }
        int col = nt * 16 + lrow;
        #pragma unroll
        for (int r = 0; r < 4; ++r) {
            int lr2 = quad * 4 + r;
            float o = fmaxf(acc[r], 0.f);
            if (LAST) {
                hs[lr2 * 264 + col] = o;
            } else {
                h8_out[(size_t)(r0 + lr2) * NHID + col] = f2fp8(o);
            }
        }
    }

    // ---- phase 3 (LAST only): logits + log_softmax, in-block ----
    if (LAST) {
        __syncthreads();
        #pragma unroll 1
        for (int rr = 0; rr < 2; ++rr) {
            int lr = wv * 2 + rr;
            const float* hr = hs + lr * 264;
            float logit = -1e30f;
            if (lane < NCLASS) {
                float acc = b1[lane];
                #pragma unroll 8
                for (int k = 0; k < NHID; ++k)
                    acc = fmaf(hr[k], w1[k * NCLASS + lane], acc);
                logit = acc;
            }
            float m = logit;
            #pragma unroll
            for (int off = 32; off > 0; off >>= 1)
                m = fmaxf(m, __shfl_xor(m, off, 64));
            float e = (lane < NCLASS) ? expf(logit - m) : 0.0f;
            float ssum = e;
            #pragma unroll
            for (int off = 32; off > 0; off >>= 1)
                ssum += __shfl_xor(ssum, off, 64);
            float lse = m + logf(ssum);
            if (lane < NCLASS)
                out[(size_t)(r0 + lr) * NCLASS + lane] = logit - lse;
        }
    }
}

// ---------------------------------------------------------------------------
extern "C" void kernel_launch(void* const* d_in, const int* in_sizes, int n_in,
                              void* d_out, int out_size, void* d_ws, size_t ws_size,
                              hipStream_t stream) {
    const float* x      = (const float*)d_in[0];
    const float* adj    = (const float*)d_in[1];
    const float* w0     = (const float*)d_in[2];
    const float* b0     = (const float*)d_in[3];
    const float* conv_w = (const float*)d_in[4];
    const float* w1     = (const float*)d_in[5];
    const float* b1     = (const float*)d_in[6];
    float* out = (float*)d_out;

    char* ws = (char*)d_ws;
    size_t off = 0;
    auto alloc = [&](size_t bytes) -> void* {
        void* p = ws + off;
        off = (off + bytes + 255) & ~(size_t)255;
        return p;
    };
    float*          dinv  = (float*)alloc((size_t)NN * 4);
    int*            cnt   = (int*)  alloc((size_t)NN * 4);
    int*            ell   = (int*)  alloc((size_t)NN * MAXDEG * 4);
    float*          scl_g = (float*)alloc((size_t)NN * MAXDEG * 4);
    unsigned short* w0t   = (unsigned short*)alloc((size_t)NFEAT * NHID * 2);
    unsigned short* Mt    = (unsigned short*)alloc((size_t)NLAYERS * NHID * NHID * 2);
    unsigned short* h0b   = (unsigned short*)alloc((size_t)NN * NHID * 2);
    unsigned int*   h08   = (unsigned int*)alloc((size_t)NN * NHID);
    unsigned int*   hP8   = (unsigned int*)alloc((size_t)NN * NHID);
    unsigned int*   hQ8   = (unsigned int*)alloc((size_t)NN * NHID);

    build_graph<<<NN, 256, 0, stream>>>(adj, cnt, ell, dinv);
    prep_weights<<<(131072 + NLAYERS * NHID * NHID) / 256, 256, 0, stream>>>(w0, conv_w, w0t, Mt);
    prep_ell<<<(NN * MAXDEG + 255) / 256, 256, 0, stream>>>(ell, cnt, dinv, scl_g);
    gemm0_mfma<<<NN / 16, 512, 0, stream>>>(x, w0t, b0, h0b, (unsigned char*)h08);

    const unsigned int* hc8 = h08;
    for (int l = 0; l < NLAYERS; ++l) {
        unsigned int* nxt = (l & 1) ? hQ8 : hP8;
        const unsigned short* wt = Mt + (size_t)l * NHID * NHID;
        if (l == NLAYERS - 1)
            layer_fused<true><<<NN / 16, 512, 0, stream>>>(hc8, h0b, dinv, cnt, ell, scl_g, wt, w1, b1, nullptr, out);
        else
            layer_fused<false><<<NN / 16, 512, 0, stream>>>(hc8, h0b, dinv, cnt, ell, scl_g, wt, nullptr, nullptr, (unsigned char*)nxt, nullptr);
        hc8 = nxt;
    }
}